// Round 11
// baseline (11393.110 us; speedup 1.0000x reference)
//
#include <hip/hip_runtime.h>
#include <stdint.h>

#define NEG_SLOPE 0.2f
#define SEPS 1e-16f

static __device__ __forceinline__ float bf2f(ushort u) {
  union { uint32_t i; float f; } v; v.i = ((uint32_t)u) << 16; return v.f;
}
static __device__ __forceinline__ ushort f2bf(float f) {
  uint32_t b = __float_as_uint(f);
  b += 0x7FFFu + ((b >> 16) & 1u);      // RNE
  return (ushort)(b >> 16);
}
static __device__ __forceinline__ float ldf(const void* p, size_t i, int mode) {
  return mode ? ((const float*)p)[i] : bf2f(((const ushort*)p)[i]);
}
// CAS-based float atomic max (init with -1e30 sentinel)
static __device__ __forceinline__ void atomicMaxCAS(float* a, float v) {
  int* ai = (int*)a;
  int old = __float_as_int(*a);
  while (__int_as_float(old) < v) {
    int assumed = old;
    old = atomicCAS(ai, assumed, __float_as_int(v));
    if (old == assumed) break;
  }
}

// ---------------- diagnostics / fills (fp32 output now!) ----------------
__global__ void fill_out(float* __restrict__ out, int n, float v) {
  int i = blockIdx.x * 256 + threadIdx.x;
  if (i < n) out[i] = v;
}
__global__ void fill_f32(float* __restrict__ p, int n, float v) {
  int i = blockIdx.x * 256 + threadIdx.x;
  if (i < n) p[i] = v;
}

// ---------------- storage detectors (proven R5-R9) ----------------
__global__ void detect_store(const uint32_t* __restrict__ w, int elems,
                             int* __restrict__ mode) {
  __shared__ int sL, sH;
  if (threadIdx.x == 0) { sL = 0; sH = 0; }
  __syncthreads();
  int nprobe = min(2048, elems / 2);
  int cL = 0, cH = 0;
  for (int i = threadIdx.x; i < nprobe; i += 256) {
    uint32_t v = w[i];
    uint32_t eL = (v >> 7) & 0xFFu;
    uint32_t eH = (v >> 23) & 0xFFu;
    if (eL >= 90u && eL <= 128u) cL++;
    if (eH >= 90u && eH <= 128u) cH++;
  }
  atomicAdd(&sL, cL); atomicAdd(&sH, cH);
  __syncthreads();
  if (threadIdx.x == 0) {
    int m;
    if (sL * 4 >= nprobe * 3) m = 0;
    else if (sH * 4 >= nprobe) m = 1;
    else m = 0;
    *mode = m;
  }
}
__global__ void detect_i64(const uint32_t* __restrict__ w, int elems,
                           int* __restrict__ mode) {
  __shared__ int sz;
  if (threadIdx.x == 0) sz = 0;
  __syncthreads();
  int nprobe = min(4096, elems);
  int c = 0;
  for (int i = threadIdx.x; i < nprobe; i += 256)
    if ((i & 1) && w[i] == 0u) c++;
  atomicAdd(&sz, c);
  __syncthreads();
  if (threadIdx.x == 0) *mode = (sz * 4 >= (nprobe / 2) * 3) ? 1 : 0;
}

// ---------------- canonicalizers ----------------
// Reference orientation: src = edge_index[0], dst = edge_index[1],
// aggregate at dst (xi = xp[dst], xj = xp[src], segment over dst).
__global__ void canon_idx(const void* __restrict__ ei, int* __restrict__ srcc,
                          int* __restrict__ dstc, int E, int N,
                          const int* __restrict__ m64) {
  int i = blockIdx.x * 256 + threadIdx.x;
  if (i >= E) return;
  int s, d;
  if (*m64) {
    s = (int)((const long long*)ei)[i];
    d = (int)((const long long*)ei)[E + i];
  } else {
    s = ((const int*)ei)[i];
    d = ((const int*)ei)[E + i];
  }
  srcc[i] = min(max(s, 0), N - 1);
  dstc[i] = min(max(d, 0), N - 1);
}
__global__ void canon_f32(const void* __restrict__ in, float* __restrict__ out,
                          int n, const int* __restrict__ mode) {
  int i = blockIdx.x * 256 + threadIdx.x;
  if (i >= n) return;
  float v = ldf(in, i, *mode);
  if (!isfinite(v)) v = 0.f;
  out[i] = v;
}
__global__ void transpose_f32(const void* __restrict__ in, float* __restrict__ out,
                              int R, int C, const int* __restrict__ mode) {
  int idx = blockIdx.x * 256 + threadIdx.x;
  if (idx >= R * C) return;
  int r = idx / C, c = idx % C;
  float v = ldf(in, idx, *mode);
  if (!isfinite(v)) v = 0.f;
  out[(size_t)c * R + r] = v;
}

// ---------------- GEMM1: xp_bf[M,256] = X[M,512] @ W1 (fp32 acc) ----------
__global__ __launch_bounds__(256) void gemm1(const void* __restrict__ X,
                                             const float* __restrict__ WT,
                                             ushort* __restrict__ out,
                                             int M, int K, int Nn,
                                             const int* __restrict__ modeX) {
  int t = threadIdx.x;
  int m0 = blockIdx.x * 4;
  const float* wr = WT + (size_t)t * K;
  float a0 = 0, a1 = 0, a2 = 0, a3 = 0;
  if (*modeX) {
    const float* Xf = (const float*)X;
    for (int k = 0; k < K; ++k) {
      float w = wr[k];
      a0 += Xf[(size_t)(m0 + 0) * K + k] * w;
      a1 += Xf[(size_t)(m0 + 1) * K + k] * w;
      a2 += Xf[(size_t)(m0 + 2) * K + k] * w;
      a3 += Xf[(size_t)(m0 + 3) * K + k] * w;
    }
  } else {
    const ushort* Xb = (const ushort*)X;
    for (int k = 0; k < K; ++k) {
      float w = wr[k];
      a0 += bf2f(Xb[(size_t)(m0 + 0) * K + k]) * w;
      a1 += bf2f(Xb[(size_t)(m0 + 1) * K + k]) * w;
      a2 += bf2f(Xb[(size_t)(m0 + 2) * K + k]) * w;
      a3 += bf2f(Xb[(size_t)(m0 + 3) * K + k]) * w;
    }
  }
  out[(size_t)(m0 + 0) * Nn + t] = f2bf(a0);
  out[(size_t)(m0 + 1) * Nn + t] = f2bf(a1);
  out[(size_t)(m0 + 2) * Nn + t] = f2bf(a2);
  out[(size_t)(m0 + 3) * Nn + t] = f2bf(a3);
}

// ---------------- GEMM2: hp_bf[M,128] = H[M,256](fp32) @ W ----------------
__global__ __launch_bounds__(128) void gemm2(const float* __restrict__ A,
                                             const float* __restrict__ WT,
                                             ushort* __restrict__ out,
                                             int M, int K, int Nn) {
  int t = threadIdx.x;
  int m0 = blockIdx.x * 4;
  const float* wr = WT + (size_t)t * K;
  float a0 = 0, a1 = 0, a2 = 0, a3 = 0;
  for (int k = 0; k < K; ++k) {
    float w = wr[k];
    a0 += A[(size_t)(m0 + 0) * K + k] * w;
    a1 += A[(size_t)(m0 + 1) * K + k] * w;
    a2 += A[(size_t)(m0 + 2) * K + k] * w;
    a3 += A[(size_t)(m0 + 3) * K + k] * w;
  }
  out[(size_t)(m0 + 0) * Nn + t] = f2bf(a0);
  out[(size_t)(m0 + 1) * Nn + t] = f2bf(a1);
  out[(size_t)(m0 + 2) * Nn + t] = f2bf(a2);
  out[(size_t)(m0 + 3) * Nn + t] = f2bf(a3);
}

// ---------------- node dots (scalar) ----------------
__global__ void node_dots1(const ushort* __restrict__ xp, const float* __restrict__ att,
                           float* __restrict__ ad, float* __restrict__ as_, int N) {
  int idx = blockIdx.x * 256 + threadIdx.x;
  if (idx >= N * 8) return;
  int half = idx & 1, h = (idx >> 1) & 3, n = idx >> 3;
  const ushort* row = xp + (size_t)n * 256 + h * 64;
  const float* wv = att + h * 128 + half * 64;
  float s = 0.f;
  for (int c = 0; c < 64; ++c) s += bf2f(row[c]) * wv[c];
  if (half == 0) ad[n * 4 + h] = s;
  else           as_[n * 4 + h] = s;
}
__global__ void node_dots2(const ushort* __restrict__ hpmu, const ushort* __restrict__ hplv,
                           const float* __restrict__ attmu, const float* __restrict__ attlv,
                           float* __restrict__ a4, int N) {
  int idx = blockIdx.x * 256 + threadIdx.x;
  if (idx >= N * 4) return;
  int w = idx & 3, n = idx >> 2;
  const ushort* hp = (w < 2) ? hpmu : hplv;
  const float* at = (w < 2) ? attmu : attlv;
  const float* wv = at + ((w & 1) ? 128 : 0);
  const ushort* row = hp + (size_t)n * 128;
  float s = 0.f;
  for (int c = 0; c < 128; ++c) s += bf2f(row[c]) * wv[c];
  a4[idx] = s;
}

// ---------------- layer-1 edge kernels: one thread per (e,h) ---------------
__global__ void emax1(const int* __restrict__ srcv, const int* __restrict__ dstv,
                      const float* __restrict__ ad, const float* __restrict__ as_,
                      float* __restrict__ amax, int E) {
  int i = blockIdx.x * 256 + threadIdx.x;
  if (i >= E * 4) return;
  int h = i & 3, e = i >> 2;
  float a = ad[dstv[e] * 4 + h] + as_[srcv[e] * 4 + h];
  a = a >= 0.f ? a : NEG_SLOPE * a;
  atomicMaxCAS(&amax[dstv[e] * 4 + h], a);
}
__global__ void epass1(const int* __restrict__ srcv, const int* __restrict__ dstv,
                       const float* __restrict__ ad, const float* __restrict__ as_,
                       const float* __restrict__ amax,
                       float* __restrict__ ex, float* __restrict__ denom, int E) {
  int i = blockIdx.x * 256 + threadIdx.x;
  if (i >= E * 4) return;
  int h = i & 3, e = i >> 2;
  int d = dstv[e];
  float a = ad[d * 4 + h] + as_[srcv[e] * 4 + h];
  a = a >= 0.f ? a : NEG_SLOPE * a;
  float ev = expf(a - amax[d * 4 + h]);
  ex[(size_t)e * 4 + h] = ev;
  atomicAdd(&denom[d * 4 + h], ev);
}
__global__ void eagg1(const int* __restrict__ srcv, const int* __restrict__ dstv,
                      const float* __restrict__ ew, const float* __restrict__ ex,
                      const float* __restrict__ denom, const ushort* __restrict__ xp,
                      float* __restrict__ agg, int E) {
  int i = blockIdx.x * 256 + threadIdx.x;
  if (i >= E * 4) return;
  int h = i & 3, e = i >> 2;
  int d = dstv[e], s = srcv[e];
  float coeff = ex[(size_t)e * 4 + h] / (denom[d * 4 + h] + SEPS) * ew[e];
  const ushort* xr = xp + (size_t)s * 256 + h * 64;
  float* ar = agg + (size_t)d * 256 + h * 64;
  for (int c = 0; c < 64; ++c)
    atomicAdd(&ar[c], coeff * bf2f(xr[c]));
}
__global__ void elu_bias(float* __restrict__ h, const float* __restrict__ b1, int total) {
  int i = blockIdx.x * 256 + threadIdx.x;
  if (i >= total) return;
  float v = h[i] + b1[i & 255];
  h[i] = v > 0.f ? v : expm1f(v);
}

// ---------------- layer-2 edge kernels: one thread per (e,slot) ------------
__global__ void emax2(const int* __restrict__ srcv, const int* __restrict__ dstv,
                      const float* __restrict__ a4, float* __restrict__ amax2,
                      int E, int N) {
  int i = blockIdx.x * 256 + threadIdx.x;
  if (i >= E * 2) return;
  int sl = i & 1, e = i >> 1;
  int d = dstv[e];
  float a = a4[d * 4 + sl * 2] + a4[srcv[e] * 4 + sl * 2 + 1];
  a = a >= 0.f ? a : NEG_SLOPE * a;
  atomicMaxCAS(&amax2[(size_t)sl * N + d], a);
}
__global__ void epass2(const int* __restrict__ srcv, const int* __restrict__ dstv,
                       const float* __restrict__ a4, const float* __restrict__ amax2,
                       float* __restrict__ ex2, float* __restrict__ den2, int E, int N) {
  int i = blockIdx.x * 256 + threadIdx.x;
  if (i >= E * 2) return;
  int sl = i & 1, e = i >> 1;
  int d = dstv[e];
  float a = a4[d * 4 + sl * 2] + a4[srcv[e] * 4 + sl * 2 + 1];
  a = a >= 0.f ? a : NEG_SLOPE * a;
  float ev = expf(a - amax2[(size_t)sl * N + d]);
  ex2[(size_t)sl * E + e] = ev;
  atomicAdd(&den2[(size_t)sl * N + d], ev);
}
__global__ void eagg2(const int* __restrict__ srcv, const int* __restrict__ dstv,
                      const float* __restrict__ ew, const float* __restrict__ ex2,
                      const float* __restrict__ den2,
                      const ushort* __restrict__ hpmu, const ushort* __restrict__ hplv,
                      float* __restrict__ acc, int E, int N) {
  int i = blockIdx.x * 256 + threadIdx.x;
  if (i >= E * 2) return;
  int sl = i & 1, e = i >> 1;
  int d = dstv[e], s = srcv[e];
  float coeff = ex2[(size_t)sl * E + e] / (den2[(size_t)sl * N + d] + SEPS) * ew[e];
  const ushort* hr = (sl ? hplv : hpmu) + (size_t)s * 128;
  float* ar = acc + (size_t)sl * N * 128 + (size_t)d * 128;
  for (int c = 0; c < 128; ++c)
    atomicAdd(&ar[c], coeff * bf2f(hr[c]));
}
// *** fp32 output store — the round-11 fix ***
__global__ void emit(const float* __restrict__ acc, const float* __restrict__ bmu,
                     const float* __restrict__ blv, float* __restrict__ out, int N) {
  int i = blockIdx.x * 256 + threadIdx.x;
  if (i >= 2 * N * 128) return;
  int c = i & 127;
  float b = (i < N * 128) ? bmu[c] : blv[c];
  out[i] = acc[i] + b;
}

extern "C" void kernel_launch(void* const* d_in, const int* in_sizes, int n_in,
                              void* d_out, int out_size, void* d_ws, size_t ws_size,
                              hipStream_t stream) {
  int OB = (out_size + 255) / 256;
  bool ok = (n_in == 12);
  int HID = 0, IN = 0, N = 0, LAT = 0, E = 0;
  if (ok) {
    HID = in_sizes[5];
    ok = ok && HID == 256;
    IN = HID ? in_sizes[3] / HID : 0;
    ok = ok && IN == 512 && in_sizes[3] == IN * HID;
    N = IN ? in_sizes[0] / IN : 0;
    ok = ok && N > 0 && in_sizes[0] == N * IN && (N % 4) == 0;
    LAT = in_sizes[8];
    ok = ok && LAT == 128;
    E = in_sizes[2];
    ok = ok && E > 0 && in_sizes[1] == 2 * E;
    ok = ok && in_sizes[4] == 2 * HID && in_sizes[6] == HID * LAT &&
         in_sizes[7] == 2 * LAT && in_sizes[9] == HID * LAT &&
         in_sizes[10] == 2 * LAT && in_sizes[11] == LAT &&
         out_size == 2 * N * LAT;
  }
  if (!ok) { fill_out<<<OB, 256, 0, stream>>>((float*)d_out, out_size, 2.0f); return; }

  char* p = (char*)d_ws;
  auto alloc = [&](size_t bytes) -> char* {
    char* r = p;
    p += (bytes + 255) & ~((size_t)255);
    return r;
  };
  ushort* xp_bf = (ushort*)alloc((size_t)N * HID * 2);   // later: hpmu_bf/hplv_bf
  float*  hreg  = (float*) alloc((size_t)N * HID * 4);   // agg1 -> h -> mu/lv acc
  float*  W1T   = (float*) alloc((size_t)IN * HID * 4);
  float*  WmuT  = (float*) alloc((size_t)HID * LAT * 4);
  float*  WlvT  = (float*) alloc((size_t)HID * LAT * 4);
  float*  att1f = (float*) alloc((size_t)2 * HID * 4);
  float*  b1f   = (float*) alloc((size_t)HID * 4);
  float*  attmuf= (float*) alloc((size_t)2 * LAT * 4);
  float*  bmuf  = (float*) alloc((size_t)LAT * 4);
  float*  attlvf= (float*) alloc((size_t)2 * LAT * 4);
  float*  blvf  = (float*) alloc((size_t)LAT * 4);
  float*  ewf   = (float*) alloc((size_t)E * 4);
  float*  ad1   = (float*) alloc((size_t)N * 4 * 4);
  float*  as1   = (float*) alloc((size_t)N * 4 * 4);
  float*  a4    = (float*) alloc((size_t)N * 4 * 4);
  float*  ex1   = (float*) alloc((size_t)E * 4 * 4);     // later: ex2 (2E floats)
  float*  amax1 = (float*) alloc((size_t)N * 4 * 4);
  float*  denom1= (float*) alloc((size_t)N * 4 * 4);
  float*  amax2 = (float*) alloc((size_t)2 * N * 4);
  float*  den2  = (float*) alloc((size_t)2 * N * 4);
  int*    srcc  = (int*)   alloc((size_t)E * 4);
  int*    dstc  = (int*)   alloc((size_t)E * 4);
  int*    modes = (int*)   alloc(16 * 4);

  size_t need = (size_t)(p - (char*)d_ws);
  if (need > ws_size) {
    fill_out<<<OB, 256, 0, stream>>>((float*)d_out, out_size, 3.0f);
    return;
  }

  ushort* hpmu_bf = xp_bf;                       // gemm2 writes after eagg1's last xp read
  ushort* hplv_bf = xp_bf + (size_t)N * LAT;
  float*  ex2     = ex1;                         // epass2 writes after eagg1's last ex1 read
  float*  accml   = hreg;                        // mu/lv accumulators reuse h after gemm2

  // ---- detection + canonicalization ----
  const int fidx[11] = {0, 2, 3, 4, 5, 6, 7, 8, 9, 10, 11};
  for (int i = 0; i < 11; ++i)
    detect_store<<<1, 256, 0, stream>>>((const uint32_t*)d_in[fidx[i]],
                                        in_sizes[fidx[i]], &modes[i]);
  detect_i64<<<1, 256, 0, stream>>>((const uint32_t*)d_in[1], 2 * E, &modes[11]);

  int EB1 = (E + 255) / 256;
  canon_idx<<<EB1, 256, 0, stream>>>(d_in[1], srcc, dstc, E, N, &modes[11]);
  canon_f32<<<EB1, 256, 0, stream>>>(d_in[2], ewf, E, &modes[1]);
  transpose_f32<<<(IN * HID + 255) / 256, 256, 0, stream>>>(d_in[3], W1T, IN, HID, &modes[2]);
  transpose_f32<<<(HID * LAT + 255) / 256, 256, 0, stream>>>(d_in[6], WmuT, HID, LAT, &modes[5]);
  transpose_f32<<<(HID * LAT + 255) / 256, 256, 0, stream>>>(d_in[9], WlvT, HID, LAT, &modes[8]);
  canon_f32<<<2, 256, 0, stream>>>(d_in[4], att1f, 2 * HID, &modes[3]);
  canon_f32<<<1, 256, 0, stream>>>(d_in[5], b1f, HID, &modes[4]);
  canon_f32<<<1, 256, 0, stream>>>(d_in[7], attmuf, 2 * LAT, &modes[6]);
  canon_f32<<<1, 256, 0, stream>>>(d_in[8], bmuf, LAT, &modes[7]);
  canon_f32<<<1, 256, 0, stream>>>(d_in[10], attlvf, 2 * LAT, &modes[9]);
  canon_f32<<<1, 256, 0, stream>>>(d_in[11], blvf, LAT, &modes[10]);

  // ---- init fills ----
  fill_f32<<<((N * HID) + 255) / 256, 256, 0, stream>>>(hreg, N * HID, 0.f);
  fill_f32<<<((N * 4) + 255) / 256, 256, 0, stream>>>(denom1, N * 4, 0.f);
  fill_f32<<<((N * 4) + 255) / 256, 256, 0, stream>>>(amax1, N * 4, -1e30f);
  fill_f32<<<((2 * N) + 255) / 256, 256, 0, stream>>>(amax2, 2 * N, -1e30f);
  fill_f32<<<((2 * N) + 255) / 256, 256, 0, stream>>>(den2, 2 * N, 0.f);

  int EB4 = (E * 4 + 255) / 256;
  int EB2 = (E * 2 + 255) / 256;

  // ---- layer 1 ----
  gemm1<<<N / 4, 256, 0, stream>>>(d_in[0], W1T, xp_bf, N, IN, HID, &modes[0]);
  node_dots1<<<(N * 8 + 255) / 256, 256, 0, stream>>>(xp_bf, att1f, ad1, as1, N);
  emax1<<<EB4, 256, 0, stream>>>(srcc, dstc, ad1, as1, amax1, E);
  epass1<<<EB4, 256, 0, stream>>>(srcc, dstc, ad1, as1, amax1, ex1, denom1, E);
  eagg1<<<EB4, 256, 0, stream>>>(srcc, dstc, ewf, ex1, denom1, xp_bf, hreg, E);
  elu_bias<<<((N * HID) + 255) / 256, 256, 0, stream>>>(hreg, b1f, N * HID);

  // ---- layer 2 ----
  gemm2<<<N / 4, 128, 0, stream>>>(hreg, WmuT, hpmu_bf, N, HID, LAT);
  gemm2<<<N / 4, 128, 0, stream>>>(hreg, WlvT, hplv_bf, N, HID, LAT);
  fill_f32<<<((2 * N * LAT) + 255) / 256, 256, 0, stream>>>(accml, 2 * N * LAT, 0.f);
  node_dots2<<<(N * 4 + 255) / 256, 256, 0, stream>>>(hpmu_bf, hplv_bf, attmuf, attlvf, a4, N);
  emax2<<<EB2, 256, 0, stream>>>(srcc, dstc, a4, amax2, E, N);
  epass2<<<EB2, 256, 0, stream>>>(srcc, dstc, a4, amax2, ex2, den2, E, N);
  eagg2<<<EB2, 256, 0, stream>>>(srcc, dstc, ewf, ex2, den2, hpmu_bf, hplv_bf, accml, E, N);
  emit<<<(2 * N * LAT + 255) / 256, 256, 0, stream>>>(accml, bmuf, blvf, (float*)d_out, N);
}

// Round 12
// 3203.754 us; speedup vs baseline: 3.5562x; 3.5562x over previous
//
#include <hip/hip_runtime.h>
#include <stdint.h>

#define NEG_SLOPE 0.2f
#define SEPS 1e-16f

static __device__ __forceinline__ float bf2f(ushort u) {
  union { uint32_t i; float f; } v; v.i = ((uint32_t)u) << 16; return v.f;
}
static __device__ __forceinline__ ushort f2bf(float f) {
  uint32_t b = __float_as_uint(f);
  b += 0x7FFFu + ((b >> 16) & 1u);      // RNE
  return (ushort)(b >> 16);
}
static __device__ __forceinline__ float ldf(const void* p, size_t i, int mode) {
  return mode ? ((const float*)p)[i] : bf2f(((const ushort*)p)[i]);
}
static __device__ __forceinline__ void atomicMaxCAS(float* a, float v) {
  int* ai = (int*)a;
  int old = __float_as_int(*a);
  while (__int_as_float(old) < v) {
    int assumed = old;
    old = atomicCAS(ai, assumed, __float_as_int(v));
    if (old == assumed) break;
  }
}

// ---------------- fills ----------------
__global__ void fill_out(float* __restrict__ out, int n, float v) {
  int i = blockIdx.x * 256 + threadIdx.x;
  if (i < n) out[i] = v;
}
__global__ void fill_f32(float* __restrict__ p, int n, float v) {
  int i = blockIdx.x * 256 + threadIdx.x;
  if (i < n) p[i] = v;
}
__global__ void fill_i32(int* __restrict__ p, int n, int v) {
  int i = blockIdx.x * 256 + threadIdx.x;
  if (i < n) p[i] = v;
}

// ---------------- storage detectors (proven R5-R11) ----------------
__global__ void detect_store(const uint32_t* __restrict__ w, int elems,
                             int* __restrict__ mode) {
  __shared__ int sL, sH;
  if (threadIdx.x == 0) { sL = 0; sH = 0; }
  __syncthreads();
  int nprobe = min(2048, elems / 2);
  int cL = 0, cH = 0;
  for (int i = threadIdx.x; i < nprobe; i += 256) {
    uint32_t v = w[i];
    uint32_t eL = (v >> 7) & 0xFFu;
    uint32_t eH = (v >> 23) & 0xFFu;
    if (eL >= 90u && eL <= 128u) cL++;
    if (eH >= 90u && eH <= 128u) cH++;
  }
  atomicAdd(&sL, cL); atomicAdd(&sH, cH);
  __syncthreads();
  if (threadIdx.x == 0) {
    int m;
    if (sL * 4 >= nprobe * 3) m = 0;
    else if (sH * 4 >= nprobe) m = 1;
    else m = 0;
    *mode = m;
  }
}
__global__ void detect_i64(const uint32_t* __restrict__ w, int elems,
                           int* __restrict__ mode) {
  __shared__ int sz;
  if (threadIdx.x == 0) sz = 0;
  __syncthreads();
  int nprobe = min(4096, elems);
  int c = 0;
  for (int i = threadIdx.x; i < nprobe; i += 256)
    if ((i & 1) && w[i] == 0u) c++;
  atomicAdd(&sz, c);
  __syncthreads();
  if (threadIdx.x == 0) *mode = (sz * 4 >= (nprobe / 2) * 3) ? 1 : 0;
}

// ---------------- canonicalizers ----------------
__global__ void canon_idx(const void* __restrict__ ei, int* __restrict__ srcc,
                          int* __restrict__ dstc, int E, int N,
                          const int* __restrict__ m64) {
  int i = blockIdx.x * 256 + threadIdx.x;
  if (i >= E) return;
  int s, d;
  if (*m64) {
    s = (int)((const long long*)ei)[i];
    d = (int)((const long long*)ei)[E + i];
  } else {
    s = ((const int*)ei)[i];
    d = ((const int*)ei)[E + i];
  }
  srcc[i] = min(max(s, 0), N - 1);
  dstc[i] = min(max(d, 0), N - 1);
}
__global__ void canon_f32(const void* __restrict__ in, float* __restrict__ out,
                          int n, const int* __restrict__ mode) {
  int i = blockIdx.x * 256 + threadIdx.x;
  if (i >= n) return;
  float v = ldf(in, i, *mode);
  if (!isfinite(v)) v = 0.f;
  out[i] = v;
}
__global__ void transpose_f32(const void* __restrict__ in, float* __restrict__ out,
                              int R, int C, const int* __restrict__ mode) {
  int idx = blockIdx.x * 256 + threadIdx.x;
  if (idx >= R * C) return;
  int r = idx / C, c = idx % C;
  float v = ldf(in, idx, *mode);
  if (!isfinite(v)) v = 0.f;
  out[(size_t)c * R + r] = v;
}

// ---------------- CSR build (proven R1-R7) ----------------
__global__ void count_deg(const int* __restrict__ dstv, int* __restrict__ deg, int E) {
  int e = blockIdx.x * 256 + threadIdx.x;
  if (e < E) atomicAdd(&deg[dstv[e]], 1);
}
__global__ __launch_bounds__(1024) void scan_deg(const int* __restrict__ deg,
                                                 int* __restrict__ row_ptr,
                                                 int* __restrict__ row_cur, int N) {
  __shared__ int part[1024];
  int t = threadIdx.x;
  int chunk = (N + 1023) / 1024;
  int lo = t * chunk, hi = min(lo + chunk, N);
  int s = 0;
  for (int i = lo; i < hi; ++i) s += deg[i];
  part[t] = s;
  __syncthreads();
  for (int off = 1; off < 1024; off <<= 1) {
    int v = (t >= off) ? part[t - off] : 0;
    __syncthreads();
    part[t] += v;
    __syncthreads();
  }
  int base = (t == 0) ? 0 : part[t - 1];
  for (int i = lo; i < hi; ++i) {
    row_ptr[i] = base; row_cur[i] = base;
    base += deg[i];
  }
  if (t == 1023) row_ptr[N] = part[1023];
}
__global__ void scatter_edges(const int* __restrict__ dstv, int* __restrict__ row_cur,
                              int* __restrict__ csr_e, int E) {
  int e = blockIdx.x * 256 + threadIdx.x;
  if (e < E) {
    int p = atomicAdd(&row_cur[dstv[e]], 1);
    csr_e[p] = e;
  }
}

// ---------------- GEMM1: xp_bf[M,256] = X[M,512] @ W1 (fp32 acc) ----------
__global__ __launch_bounds__(256) void gemm1(const void* __restrict__ X,
                                             const float* __restrict__ WT,
                                             ushort* __restrict__ out,
                                             int M, int K, int Nn,
                                             const int* __restrict__ modeX) {
  int t = threadIdx.x;
  int m0 = blockIdx.x * 4;
  const float* wr = WT + (size_t)t * K;
  float a0 = 0, a1 = 0, a2 = 0, a3 = 0;
  if (*modeX) {
    const float* Xf = (const float*)X;
    for (int k = 0; k < K; ++k) {
      float w = wr[k];
      a0 += Xf[(size_t)(m0 + 0) * K + k] * w;
      a1 += Xf[(size_t)(m0 + 1) * K + k] * w;
      a2 += Xf[(size_t)(m0 + 2) * K + k] * w;
      a3 += Xf[(size_t)(m0 + 3) * K + k] * w;
    }
  } else {
    const ushort* Xb = (const ushort*)X;
    for (int k = 0; k < K; ++k) {
      float w = wr[k];
      a0 += bf2f(Xb[(size_t)(m0 + 0) * K + k]) * w;
      a1 += bf2f(Xb[(size_t)(m0 + 1) * K + k]) * w;
      a2 += bf2f(Xb[(size_t)(m0 + 2) * K + k]) * w;
      a3 += bf2f(Xb[(size_t)(m0 + 3) * K + k]) * w;
    }
  }
  out[(size_t)(m0 + 0) * Nn + t] = f2bf(a0);
  out[(size_t)(m0 + 1) * Nn + t] = f2bf(a1);
  out[(size_t)(m0 + 2) * Nn + t] = f2bf(a2);
  out[(size_t)(m0 + 3) * Nn + t] = f2bf(a3);
}

// ---------------- GEMM2: hp_bf[M,128] = H[M,256](fp32) @ W ----------------
__global__ __launch_bounds__(128) void gemm2(const float* __restrict__ A,
                                             const float* __restrict__ WT,
                                             ushort* __restrict__ out,
                                             int M, int K, int Nn) {
  int t = threadIdx.x;
  int m0 = blockIdx.x * 4;
  const float* wr = WT + (size_t)t * K;
  float a0 = 0, a1 = 0, a2 = 0, a3 = 0;
  for (int k = 0; k < K; ++k) {
    float w = wr[k];
    a0 += A[(size_t)(m0 + 0) * K + k] * w;
    a1 += A[(size_t)(m0 + 1) * K + k] * w;
    a2 += A[(size_t)(m0 + 2) * K + k] * w;
    a3 += A[(size_t)(m0 + 3) * K + k] * w;
  }
  out[(size_t)(m0 + 0) * Nn + t] = f2bf(a0);
  out[(size_t)(m0 + 1) * Nn + t] = f2bf(a1);
  out[(size_t)(m0 + 2) * Nn + t] = f2bf(a2);
  out[(size_t)(m0 + 3) * Nn + t] = f2bf(a3);
}

// ---------------- node dots (scalar) ----------------
__global__ void node_dots1(const ushort* __restrict__ xp, const float* __restrict__ att,
                           float* __restrict__ ad, float* __restrict__ as_, int N) {
  int idx = blockIdx.x * 256 + threadIdx.x;
  if (idx >= N * 8) return;
  int half = idx & 1, h = (idx >> 1) & 3, n = idx >> 3;
  const ushort* row = xp + (size_t)n * 256 + h * 64;
  const float* wv = att + h * 128 + half * 64;
  float s = 0.f;
  for (int c = 0; c < 64; ++c) s += bf2f(row[c]) * wv[c];
  if (half == 0) ad[n * 4 + h] = s;
  else           as_[n * 4 + h] = s;
}
__global__ void node_dots2(const ushort* __restrict__ hpmu, const ushort* __restrict__ hplv,
                           const float* __restrict__ attmu, const float* __restrict__ attlv,
                           float* __restrict__ a4, int N) {
  int idx = blockIdx.x * 256 + threadIdx.x;
  if (idx >= N * 4) return;
  int w = idx & 3, n = idx >> 2;
  const ushort* hp = (w < 2) ? hpmu : hplv;
  const float* at = (w < 2) ? attmu : attlv;
  const float* wv = at + ((w & 1) ? 128 : 0);
  const ushort* row = hp + (size_t)n * 128;
  float s = 0.f;
  for (int c = 0; c < 128; ++c) s += bf2f(row[c]) * wv[c];
  a4[idx] = s;
}

// ---------------- layer-1 edge kernels (unchanged) ----------------
__global__ void emax1(const int* __restrict__ srcv, const int* __restrict__ dstv,
                      const float* __restrict__ ad, const float* __restrict__ as_,
                      float* __restrict__ amax, int E) {
  int i = blockIdx.x * 256 + threadIdx.x;
  if (i >= E * 4) return;
  int h = i & 3, e = i >> 2;
  float a = ad[dstv[e] * 4 + h] + as_[srcv[e] * 4 + h];
  a = a >= 0.f ? a : NEG_SLOPE * a;
  atomicMaxCAS(&amax[dstv[e] * 4 + h], a);
}
__global__ void epass1(const int* __restrict__ srcv, const int* __restrict__ dstv,
                       const float* __restrict__ ad, const float* __restrict__ as_,
                       const float* __restrict__ amax,
                       float* __restrict__ ex, float* __restrict__ denom, int E) {
  int i = blockIdx.x * 256 + threadIdx.x;
  if (i >= E * 4) return;
  int h = i & 3, e = i >> 2;
  int d = dstv[e];
  float a = ad[d * 4 + h] + as_[srcv[e] * 4 + h];
  a = a >= 0.f ? a : NEG_SLOPE * a;
  float ev = expf(a - amax[d * 4 + h]);
  ex[(size_t)e * 4 + h] = ev;
  atomicAdd(&denom[d * 4 + h], ev);
}

// ---------------- layer-1 CSR aggregation + bias + ELU (atomic-free) -------
__global__ __launch_bounds__(256) void aggregate1_csr(
    const int* __restrict__ row_ptr, const int* __restrict__ csr_e,
    const int* __restrict__ srcv, const float* __restrict__ ew,
    const float* __restrict__ ex, const float* __restrict__ denom,
    const ushort* __restrict__ xp, const float* __restrict__ b1,
    float* __restrict__ hout) {
  int n = blockIdx.x;
  int t = threadIdx.x;          // channel 0..255, head = t>>6
  int h = t >> 6;
  float inv = 1.0f / (denom[n * 4 + h] + SEPS);
  float acc = 0.f;
  int lo = row_ptr[n], hi = row_ptr[n + 1];
  for (int i = lo; i < hi; ++i) {
    int e = csr_e[i];
    int s = srcv[e];
    float coeff = ex[(size_t)e * 4 + h] * inv * ew[e];
    acc += coeff * bf2f(xp[(size_t)s * 256 + t]);
  }
  float val = acc + b1[t];
  hout[(size_t)n * 256 + t] = val > 0.f ? val : expm1f(val);
}

// ---------------- layer-2 edge kernels (unchanged) ----------------
__global__ void emax2(const int* __restrict__ srcv, const int* __restrict__ dstv,
                      const float* __restrict__ a4, float* __restrict__ amax2,
                      int E, int N) {
  int i = blockIdx.x * 256 + threadIdx.x;
  if (i >= E * 2) return;
  int sl = i & 1, e = i >> 1;
  int d = dstv[e];
  float a = a4[d * 4 + sl * 2] + a4[srcv[e] * 4 + sl * 2 + 1];
  a = a >= 0.f ? a : NEG_SLOPE * a;
  atomicMaxCAS(&amax2[(size_t)sl * N + d], a);
}
__global__ void epass2(const int* __restrict__ srcv, const int* __restrict__ dstv,
                       const float* __restrict__ a4, const float* __restrict__ amax2,
                       float* __restrict__ ex2, float* __restrict__ den2, int E, int N) {
  int i = blockIdx.x * 256 + threadIdx.x;
  if (i >= E * 2) return;
  int sl = i & 1, e = i >> 1;
  int d = dstv[e];
  float a = a4[d * 4 + sl * 2] + a4[srcv[e] * 4 + sl * 2 + 1];
  a = a >= 0.f ? a : NEG_SLOPE * a;
  float ev = expf(a - amax2[(size_t)sl * N + d]);
  ex2[(size_t)sl * E + e] = ev;
  atomicAdd(&den2[(size_t)sl * N + d], ev);
}

// ---------------- layer-2 CSR aggregation + bias -> fp32 out ---------------
__global__ __launch_bounds__(256) void aggregate2_csr(
    const int* __restrict__ row_ptr, const int* __restrict__ csr_e,
    const int* __restrict__ srcv, const float* __restrict__ ew,
    const float* __restrict__ ex2, const float* __restrict__ den2,
    const ushort* __restrict__ hpmu, const ushort* __restrict__ hplv,
    const float* __restrict__ bmu, const float* __restrict__ blv,
    float* __restrict__ out, int E, int N) {
  int n = blockIdx.x;
  int t = threadIdx.x;
  int sl = t >> 7;              // 0 = mu, 1 = lv
  int c = t & 127;
  const ushort* hp = sl ? hplv : hpmu;
  float inv = 1.0f / (den2[(size_t)sl * N + n] + SEPS);
  float acc = 0.f;
  int lo = row_ptr[n], hi = row_ptr[n + 1];
  for (int i = lo; i < hi; ++i) {
    int e = csr_e[i];
    int s = srcv[e];
    float coeff = ex2[(size_t)sl * E + e] * inv * ew[e];
    acc += coeff * bf2f(hp[(size_t)s * 128 + c]);
  }
  out[(size_t)sl * N * 128 + (size_t)n * 128 + c] = acc + (sl ? blv[c] : bmu[c]);
}

extern "C" void kernel_launch(void* const* d_in, const int* in_sizes, int n_in,
                              void* d_out, int out_size, void* d_ws, size_t ws_size,
                              hipStream_t stream) {
  int OB = (out_size + 255) / 256;
  bool ok = (n_in == 12);
  int HID = 0, IN = 0, N = 0, LAT = 0, E = 0;
  if (ok) {
    HID = in_sizes[5];
    ok = ok && HID == 256;
    IN = HID ? in_sizes[3] / HID : 0;
    ok = ok && IN == 512 && in_sizes[3] == IN * HID;
    N = IN ? in_sizes[0] / IN : 0;
    ok = ok && N > 0 && in_sizes[0] == N * IN && (N % 4) == 0;
    LAT = in_sizes[8];
    ok = ok && LAT == 128;
    E = in_sizes[2];
    ok = ok && E > 0 && in_sizes[1] == 2 * E;
    ok = ok && in_sizes[4] == 2 * HID && in_sizes[6] == HID * LAT &&
         in_sizes[7] == 2 * LAT && in_sizes[9] == HID * LAT &&
         in_sizes[10] == 2 * LAT && in_sizes[11] == LAT &&
         out_size == 2 * N * LAT;
  }
  if (!ok) { fill_out<<<OB, 256, 0, stream>>>((float*)d_out, out_size, 2.0f); return; }

  char* p = (char*)d_ws;
  auto alloc = [&](size_t bytes) -> char* {
    char* r = p;
    p += (bytes + 255) & ~((size_t)255);
    return r;
  };
  ushort* xp_bf = (ushort*)alloc((size_t)N * HID * 2);   // later: hpmu_bf/hplv_bf
  float*  hreg  = (float*) alloc((size_t)N * HID * 4);
  float*  W1T   = (float*) alloc((size_t)IN * HID * 4);
  float*  WmuT  = (float*) alloc((size_t)HID * LAT * 4);
  float*  WlvT  = (float*) alloc((size_t)HID * LAT * 4);
  float*  att1f = (float*) alloc((size_t)2 * HID * 4);
  float*  b1f   = (float*) alloc((size_t)HID * 4);
  float*  attmuf= (float*) alloc((size_t)2 * LAT * 4);
  float*  bmuf  = (float*) alloc((size_t)LAT * 4);
  float*  attlvf= (float*) alloc((size_t)2 * LAT * 4);
  float*  blvf  = (float*) alloc((size_t)LAT * 4);
  float*  ewf   = (float*) alloc((size_t)E * 4);
  float*  ad1   = (float*) alloc((size_t)N * 4 * 4);
  float*  as1   = (float*) alloc((size_t)N * 4 * 4);
  float*  a4    = (float*) alloc((size_t)N * 4 * 4);
  float*  ex1   = (float*) alloc((size_t)E * 4 * 4);     // later: ex2 (2E floats)
  float*  amax1 = (float*) alloc((size_t)N * 4 * 4);
  float*  denom1= (float*) alloc((size_t)N * 4 * 4);
  float*  amax2 = (float*) alloc((size_t)2 * N * 4);
  float*  den2  = (float*) alloc((size_t)2 * N * 4);
  int*    srcc  = (int*)   alloc((size_t)E * 4);
  int*    dstc  = (int*)   alloc((size_t)E * 4);
  int*    csr_e = (int*)   alloc((size_t)E * 4);
  int*    row_ptr=(int*)   alloc((size_t)(N + 1) * 4);
  int*    row_cur=(int*)   alloc((size_t)N * 4);
  int*    deg   = (int*)   alloc((size_t)N * 4);
  int*    modes = (int*)   alloc(16 * 4);

  size_t need = (size_t)(p - (char*)d_ws);
  if (need > ws_size) {
    fill_out<<<OB, 256, 0, stream>>>((float*)d_out, out_size, 3.0f);
    return;
  }

  ushort* hpmu_bf = xp_bf;                 // gemm2 writes after aggregate1's last xp read
  ushort* hplv_bf = xp_bf + (size_t)N * LAT;
  float*  ex2     = ex1;                   // epass2 writes after aggregate1's last ex1 read

  // ---- detection + canonicalization ----
  const int fidx[11] = {0, 2, 3, 4, 5, 6, 7, 8, 9, 10, 11};
  for (int i = 0; i < 11; ++i)
    detect_store<<<1, 256, 0, stream>>>((const uint32_t*)d_in[fidx[i]],
                                        in_sizes[fidx[i]], &modes[i]);
  detect_i64<<<1, 256, 0, stream>>>((const uint32_t*)d_in[1], 2 * E, &modes[11]);

  int EB1 = (E + 255) / 256;
  canon_idx<<<EB1, 256, 0, stream>>>(d_in[1], srcc, dstc, E, N, &modes[11]);
  canon_f32<<<EB1, 256, 0, stream>>>(d_in[2], ewf, E, &modes[1]);
  transpose_f32<<<(IN * HID + 255) / 256, 256, 0, stream>>>(d_in[3], W1T, IN, HID, &modes[2]);
  transpose_f32<<<(HID * LAT + 255) / 256, 256, 0, stream>>>(d_in[6], WmuT, HID, LAT, &modes[5]);
  transpose_f32<<<(HID * LAT + 255) / 256, 256, 0, stream>>>(d_in[9], WlvT, HID, LAT, &modes[8]);
  canon_f32<<<2, 256, 0, stream>>>(d_in[4], att1f, 2 * HID, &modes[3]);
  canon_f32<<<1, 256, 0, stream>>>(d_in[5], b1f, HID, &modes[4]);
  canon_f32<<<1, 256, 0, stream>>>(d_in[7], attmuf, 2 * LAT, &modes[6]);
  canon_f32<<<1, 256, 0, stream>>>(d_in[8], bmuf, LAT, &modes[7]);
  canon_f32<<<1, 256, 0, stream>>>(d_in[10], attlvf, 2 * LAT, &modes[9]);
  canon_f32<<<1, 256, 0, stream>>>(d_in[11], blvf, LAT, &modes[10]);

  // ---- init fills (small) ----
  fill_f32<<<((N * 4) + 255) / 256, 256, 0, stream>>>(denom1, N * 4, 0.f);
  fill_f32<<<((N * 4) + 255) / 256, 256, 0, stream>>>(amax1, N * 4, -1e30f);
  fill_f32<<<((2 * N) + 255) / 256, 256, 0, stream>>>(amax2, 2 * N, -1e30f);
  fill_f32<<<((2 * N) + 255) / 256, 256, 0, stream>>>(den2, 2 * N, 0.f);
  fill_i32<<<(N + 255) / 256, 256, 0, stream>>>(deg, N, 0);

  int EB4 = (E * 4 + 255) / 256;
  int EB2 = (E * 2 + 255) / 256;

  // ---- CSR build (once; shared by both layers) ----
  count_deg<<<EB1, 256, 0, stream>>>(dstc, deg, E);
  scan_deg<<<1, 1024, 0, stream>>>(deg, row_ptr, row_cur, N);
  scatter_edges<<<EB1, 256, 0, stream>>>(dstc, row_cur, csr_e, E);

  // ---- layer 1 ----
  gemm1<<<N / 4, 256, 0, stream>>>(d_in[0], W1T, xp_bf, N, IN, HID, &modes[0]);
  node_dots1<<<(N * 8 + 255) / 256, 256, 0, stream>>>(xp_bf, att1f, ad1, as1, N);
  emax1<<<EB4, 256, 0, stream>>>(srcc, dstc, ad1, as1, amax1, E);
  epass1<<<EB4, 256, 0, stream>>>(srcc, dstc, ad1, as1, amax1, ex1, denom1, E);
  aggregate1_csr<<<N, 256, 0, stream>>>(row_ptr, csr_e, srcc, ewf, ex1, denom1,
                                        xp_bf, b1f, hreg);

  // ---- layer 2 ----
  gemm2<<<N / 4, 128, 0, stream>>>(hreg, WmuT, hpmu_bf, N, HID, LAT);
  gemm2<<<N / 4, 128, 0, stream>>>(hreg, WlvT, hplv_bf, N, HID, LAT);
  node_dots2<<<(N * 4 + 255) / 256, 256, 0, stream>>>(hpmu_bf, hplv_bf, attmuf, attlvf, a4, N);
  emax2<<<EB2, 256, 0, stream>>>(srcc, dstc, a4, amax2, E, N);
  epass2<<<EB2, 256, 0, stream>>>(srcc, dstc, a4, amax2, ex2, den2, E, N);
  aggregate2_csr<<<N, 256, 0, stream>>>(row_ptr, csr_e, srcc, ewf, ex2, den2,
                                        hpmu_bf, hplv_bf, bmuf, blvf,
                                        (float*)d_out, E, N);
}